// Round 4
// baseline (297.454 us; speedup 1.0000x reference)
//
#include <hip/hip_runtime.h>

// DerivNet2D fused MLP + forward-mode derivatives, v3b.
// A[96 = 3 bands x 32 samples][K=1024] @ W2^T[1024][512], MFMA 32x32x16 bf16.
// BK=128 (8 K-steps), A double-buffered in LDS (2x24KB), B fragment-major in L2.
// A-gen uses packed {w0,w1,b1} float4 table + hw v_cvt_pk_bf16_f32 (inline asm).

#define NXS    65536
#define SB     32
#define NBLK   2048        // NXS / SB
#define KSTEPS 8           // K=1024 / 128

typedef __attribute__((ext_vector_type(8)))  short bh8_t;   // 8 x bf16
typedef __attribute__((ext_vector_type(4)))  unsigned int u32x4;
typedef __attribute__((ext_vector_type(16))) float fx16_t;  // 32x32 accum
typedef unsigned int u32;

static __device__ __forceinline__ unsigned short f2bf(float f) {
  u32 u = __builtin_bit_cast(u32, f);
  u += 0x7FFFu + ((u >> 16) & 1u);      // RNE (prep kernel only)
  return (unsigned short)(u >> 16);
}

static __device__ __forceinline__ u32 pkbf(float lo, float hi) {
  u32 r;
  asm("v_cvt_pk_bf16_f32 %0, %1, %2" : "=v"(r) : "v"(lo), "v"(hi));
  return r;   // low 16 = bf16(lo), high 16 = bf16(hi)
}

static __device__ __forceinline__ float fast_tanh(float h) {
  float e = __expf(2.0f * h);
  return 1.0f - 2.0f / (e + 1.0f);
}

// prep: (a) W2 fp32 [512][1024] -> fragment-major bf16 frags
//   f = ((kblock*16 + nbk)*64 + q*32 + col), 16B each, holding
//   W2[n = nbk*32+col][k = 16*kblock + {4q..4q+3, 8+4q..8+4q+3}].
// (b) W1b[k] = {W1[k][0], W1[k][1], b1[k], 0} packed float4 (first 1024 threads).
__global__ void prep_all(const float* __restrict__ W2, const float* __restrict__ W1,
                         const float* __restrict__ b1, bh8_t* __restrict__ W2pT,
                         float4* __restrict__ W1b) {
  int f = blockIdx.x * 256 + threadIdx.x;      // 0..65535
  int col = f & 31;
  int q   = (f >> 5) & 1;
  int nbk = (f >> 6) & 15;
  int kb  = f >> 10;
  const float* row = W2 + (nbk * 32 + col) * 1024 + kb * 16 + 4 * q;
  float4 lo = *(const float4*)(row);
  float4 hi = *(const float4*)(row + 8);
  bh8_t o;
  o[0] = (short)f2bf(lo.x); o[1] = (short)f2bf(lo.y);
  o[2] = (short)f2bf(lo.z); o[3] = (short)f2bf(lo.w);
  o[4] = (short)f2bf(hi.x); o[5] = (short)f2bf(hi.y);
  o[6] = (short)f2bf(hi.z); o[7] = (short)f2bf(hi.w);
  W2pT[f] = o;
  if (f < 1024) {
    float2 w = *(const float2*)(W1 + 2 * f);
    W1b[f] = make_float4(w.x, w.y, b1[f], 0.0f);
  }
}

__global__ __launch_bounds__(256, 2) void fused_kernel(
    const float* __restrict__ x,  const float4* __restrict__ W1b,
    const float* __restrict__ b2, const float* __restrict__ W3,
    const float* __restrict__ b3, const bh8_t* __restrict__ Bg,
    float* __restrict__ out)
{
  __shared__ __attribute__((aligned(16))) char smem[49152 + 1536];
  const int tid  = threadIdx.x;
  const int lane = tid & 63;
  const int wave = tid >> 6;        // 0..3, owns N cols [128w, 128w+128)
  const int q    = lane >> 5;
  const int col  = lane & 31;
  const int s0   = blockIdx.x * SB;

  // A-gen role: gs = sample (minor, coalesced W1b dedup), gkb = 16-k block 0..7
  const int gs  = tid & 31;
  const int gkb = tid >> 5;
  const float2 xv = *(const float2*)(x + 2 * (s0 + gs));
  const float x0 = xv.x, x1 = xv.y;
  const int wbase = (gs * 256) | (((gkb << 1) ^ (gs & 7)) << 4);  // gqp=0 unit

  fx16_t acc[3][4];
#pragma unroll
  for (int b = 0; b < 3; ++b)
#pragma unroll
    for (int nb = 0; nb < 4; ++nb)
#pragma unroll
      for (int r = 0; r < 16; ++r) acc[b][nb][r] = 0.0f;

  auto stageA = [&](int kt, char* Ab) {
    const int k16 = kt * 128 + gkb * 16;
#pragma unroll
    for (int gqp = 0; gqp < 2; ++gqp) {
      const int kL = k16 + 4 * gqp;      // octet = {kL..kL+3, kL+8..kL+11}
      u32x4 wz, wa0, wa1;
#pragma unroll
      for (int jp = 0; jp < 2; ++jp) {
        float4 cA = W1b[kL + 2 * jp];
        float4 cB = W1b[kL + 2 * jp + 1];
        float4 cC = W1b[kL + 8 + 2 * jp];
        float4 cD = W1b[kL + 8 + 2 * jp + 1];
        float hA = fmaf(x0, cA.x, fmaf(x1, cA.y, cA.z));
        float hB = fmaf(x0, cB.x, fmaf(x1, cB.y, cB.z));
        float hC = fmaf(x0, cC.x, fmaf(x1, cC.y, cC.z));
        float hD = fmaf(x0, cD.x, fmaf(x1, cD.y, cD.z));
        float zA = fast_tanh(hA), zB = fast_tanh(hB);
        float zC = fast_tanh(hC), zD = fast_tanh(hD);
        float dA = 1.f - zA * zA, dB = 1.f - zB * zB;
        float dC = 1.f - zC * zC, dD = 1.f - zD * zD;
        wz[jp]      = pkbf(zA, zB);
        wz[2 + jp]  = pkbf(zC, zD);
        wa0[jp]     = pkbf(dA * cA.x, dB * cB.x);
        wa0[2 + jp] = pkbf(dC * cC.x, dD * cD.x);
        wa1[jp]     = pkbf(dA * cA.y, dB * cB.y);
        wa1[2 + jp] = pkbf(dC * cC.y, dD * cD.y);
      }
      char* dst = Ab + (wbase ^ (gqp << 4));
      *(u32x4*)(dst)         = wz;    // band 0: z1
      *(u32x4*)(dst + 8192)  = wa0;   // band 1: d1*W1c0
      *(u32x4*)(dst + 16384) = wa1;   // band 2: d1*W1c1
    }
  };

  stageA(0, smem);
  __syncthreads();

  for (int kt = 0; kt < KSTEPS; ++kt) {
    char* Acur = smem + (kt & 1) * 24576;
    char* Anxt = smem + ((kt + 1) & 1) * 24576;
    if (kt + 1 < KSTEPS) stageA(kt + 1, Anxt);   // VALU covers B-load latency
    const int abase = col * 256;
#pragma unroll
    for (int ks = 0; ks < 8; ++ks) {
      const int uoff = (((2 * ks + q) ^ (col & 7)) << 4);
      bh8_t a0 = *(const bh8_t*)(Acur + abase + uoff);
      bh8_t a1 = *(const bh8_t*)(Acur + abase + 8192 + uoff);
      bh8_t a2 = *(const bh8_t*)(Acur + abase + 16384 + uoff);
      const int fb = ((kt * 8 + ks) * 16 + wave * 4) * 64 + lane;
      bh8_t bf0 = Bg[fb];
      bh8_t bf1 = Bg[fb + 64];
      bh8_t bf2 = Bg[fb + 128];
      bh8_t bf3 = Bg[fb + 192];
      __builtin_amdgcn_s_setprio(1);
      acc[0][0] = __builtin_amdgcn_mfma_f32_32x32x16_bf16(a0, bf0, acc[0][0], 0, 0, 0);
      acc[1][0] = __builtin_amdgcn_mfma_f32_32x32x16_bf16(a1, bf0, acc[1][0], 0, 0, 0);
      acc[2][0] = __builtin_amdgcn_mfma_f32_32x32x16_bf16(a2, bf0, acc[2][0], 0, 0, 0);
      acc[0][1] = __builtin_amdgcn_mfma_f32_32x32x16_bf16(a0, bf1, acc[0][1], 0, 0, 0);
      acc[1][1] = __builtin_amdgcn_mfma_f32_32x32x16_bf16(a1, bf1, acc[1][1], 0, 0, 0);
      acc[2][1] = __builtin_amdgcn_mfma_f32_32x32x16_bf16(a2, bf1, acc[2][1], 0, 0, 0);
      acc[0][2] = __builtin_amdgcn_mfma_f32_32x32x16_bf16(a0, bf2, acc[0][2], 0, 0, 0);
      acc[1][2] = __builtin_amdgcn_mfma_f32_32x32x16_bf16(a1, bf2, acc[1][2], 0, 0, 0);
      acc[2][2] = __builtin_amdgcn_mfma_f32_32x32x16_bf16(a2, bf2, acc[2][2], 0, 0, 0);
      acc[0][3] = __builtin_amdgcn_mfma_f32_32x32x16_bf16(a0, bf3, acc[0][3], 0, 0, 0);
      acc[1][3] = __builtin_amdgcn_mfma_f32_32x32x16_bf16(a1, bf3, acc[1][3], 0, 0, 0);
      acc[2][3] = __builtin_amdgcn_mfma_f32_32x32x16_bf16(a2, bf3, acc[2][3], 0, 0, 0);
      __builtin_amdgcn_s_setprio(0);
    }
    __syncthreads();
  }

  // Epilogue: z2 = tanh(h2+b2), d2 = 1-z2^2; weighted reduce over n with W3.
  float b2n[4], w3n[4];
#pragma unroll
  for (int nb = 0; nb < 4; ++nb) {
    int n = wave * 128 + nb * 32 + col;
    b2n[nb] = b2[n];
    w3n[nb] = W3[n];
  }
  float* P = (float*)(smem + 49152);   // [3][32 samples][4 waves]
#pragma unroll
  for (int r = 0; r < 16; ++r) {
    const int srow_o = (r & 3) + 8 * (r >> 2) + 4 * q;   // sample 0..31
    float py = 0.f, p1 = 0.f, p2 = 0.f;
#pragma unroll
    for (int nb = 0; nb < 4; ++nb) {
      float z2 = fast_tanh(acc[0][nb][r] + b2n[nb]);
      float d2 = 1.f - z2 * z2;
      py = fmaf(w3n[nb], z2, py);
      p1 = fmaf(w3n[nb] * d2, acc[1][nb][r], p1);
      p2 = fmaf(w3n[nb] * d2, acc[2][nb][r], p2);
    }
#pragma unroll
    for (int m = 1; m < 32; m <<= 1) {
      py += __shfl_xor(py, m, 64);
      p1 += __shfl_xor(p1, m, 64);
      p2 += __shfl_xor(p2, m, 64);
    }
    if (col == 0) {
      P[0 * 128 + srow_o * 4 + wave] = py;
      P[1 * 128 + srow_o * 4 + wave] = p1;
      P[2 * 128 + srow_o * 4 + wave] = p2;
    }
  }
  __syncthreads();
  if (tid < 96) {
    const int v = tid >> 5, s = tid & 31;
    const float* Pv = P + v * 128 + s * 4;
    float sum = Pv[0] + Pv[1] + Pv[2] + Pv[3];
    const int si = s0 + s;
    if (v == 0)      out[si]           = sum + b3[0];  // y
    else if (v == 2) out[NXS + si]     = sum;          // v1 = dydx2
    else             out[2 * NXS + si] = -sum;         // v2 = -dydx1
  }
}

extern "C" void kernel_launch(void* const* d_in, const int* in_sizes, int n_in,
                              void* d_out, int out_size, void* d_ws, size_t ws_size,
                              hipStream_t stream) {
  const float* x  = (const float*)d_in[0];
  const float* W1 = (const float*)d_in[1];
  const float* b1 = (const float*)d_in[2];
  const float* W2 = (const float*)d_in[3];
  const float* b2 = (const float*)d_in[4];
  const float* W3 = (const float*)d_in[5];
  const float* b3 = (const float*)d_in[6];
  bh8_t*  W2pT = (bh8_t*)d_ws;                         // 1 MB fragment-major bf16 W2
  float4* W1b  = (float4*)((char*)d_ws + (1 << 20));   // packed {w0,w1,b1} table

  prep_all<<<256, 256, 0, stream>>>(W2, W1, b1, W2pT, W1b);
  fused_kernel<<<NBLK, 256, 0, stream>>>(
      x, W1b, b2, W3, b3, (const bh8_t*)W2pT, (float*)d_out);
}